// Round 3
// baseline (119.517 us; speedup 1.0000x reference)
//
#include <hip/hip_runtime.h>
#include <hip/hip_bf16.h>
#include <stdint.h>

#define NPIX 512
#define NBC  96
#define BM 128
#define BN 128
#define BK 32
#define NKT (NPIX / BK)   // 16
#define NWG1 (4 * 4 * NBC) // 1536 blocks for the GEMM stages

typedef __attribute__((ext_vector_type(8))) short bf16x8;
typedef __attribute__((ext_vector_type(4))) float f32x4;
typedef __attribute__((ext_vector_type(8))) unsigned short u16x8;

__device__ __forceinline__ unsigned short f2bf(float f) {
    __hip_bfloat16 h = __float2bfloat16(f);
    union { __hip_bfloat16 h; unsigned short u; } v;
    v.h = h;
    return v.u;
}

#define GLD16(g, l) __builtin_amdgcn_global_load_lds( \
    (const __attribute__((address_space(1))) void*)(const void*)(g), \
    (__attribute__((address_space(3))) void*)(void*)(l), 16, 0, 0)

// ---------------- D basis: D[k][n] = bf16(2*cos(pi*(2n+1)*k/1024)) ----------------
__global__ void k_basis(unsigned short* __restrict__ D) {
    int idx = blockIdx.x * 256 + threadIdx.x;      // 0 .. 262143
    int k = idx >> 9, n = idx & 511;
    int m = ((2 * n + 1) * k) & 2047;              // mod 4N: cos period, keeps arg small
    float ang = (float)m * 3.06796157577128218e-03f;  // pi/1024
    D[idx] = f2bf(2.0f * cosf(ang));
}

// ---------------- cvt: X fp32 -> bf16, 16 elems/thread ----------------
__global__ __launch_bounds__(256) void k_cvt(const float* __restrict__ X,
                                             unsigned short* __restrict__ Xbf) {
    size_t t = (size_t)blockIdx.x * 256 + threadIdx.x;   // 1.57M threads
    const float4* src = (const float4*)X + t * 4;
    float4 a = src[0], b = src[1], c = src[2], d = src[3];
    u16x8 w0, w1;
    w0[0] = f2bf(a.x); w0[1] = f2bf(a.y); w0[2] = f2bf(a.z); w0[3] = f2bf(a.w);
    w0[4] = f2bf(b.x); w0[5] = f2bf(b.y); w0[6] = f2bf(b.z); w0[7] = f2bf(b.w);
    w1[0] = f2bf(c.x); w1[1] = f2bf(c.y); w1[2] = f2bf(c.z); w1[3] = f2bf(c.w);
    w1[4] = f2bf(d.x); w1[5] = f2bf(d.y); w1[6] = f2bf(d.z); w1[7] = f2bf(d.w);
    u16x8* dst = (u16x8*)Xbf + t * 2;
    dst[0] = w0;
    dst[1] = w1;
}

// ---------------- Stage 1: sT[l][h] = bf16( (Xbf @ D^T)[h][l] ) ----------------
// Pure bf16, both operands via global_load_lds (identical structure to stage 2).
__global__ __launch_bounds__(256) void k_stage1(
        const unsigned short* __restrict__ Xbf,
        const unsigned short* __restrict__ D,
        unsigned short* __restrict__ sT) {
    __shared__ unsigned short As[2][BM * BK];          // bf16 X tile
    __shared__ unsigned short Bs[2][BN * BK];          // bf16 D tile

    // Bijective XCD-chunked swizzle: 1536 = 8 XCDs x 192 consecutive blocks.
    const int bid = blockIdx.x;
    const int nb  = (bid & 7) * (NWG1 / 8) + (bid >> 3);
    const int bx = nb & 3, by = (nb >> 2) & 3, bc = nb >> 4;
    const int h0 = by * BM;
    const int l0 = bx * BN;
    const unsigned short* Xbc = Xbf + (size_t)bc * NPIX * NPIX;
    unsigned short* sTbc = sT + (size_t)bc * NPIX * NPIX;

    const int tid  = threadIdx.x;
    const int lane = tid & 63;
    const int wid  = tid >> 6;
    const int wr = wid >> 1, wc = wid & 1;             // 2x2 wave grid, 64x64 each
    const int rm = lane & 15;
    const int kq = lane >> 4;

    f32x4 acc[4][4] = {};

    auto stage = [&](int kt, int buf) {
        #pragma unroll
        for (int it = 0; it < 2; ++it) {
            int chunk = it * 256 + tid;
            int r = chunk >> 2, c = chunk & 3;
            int cs = c ^ (r & 3) ^ ((r >> 2) & 3);
            GLD16(Xbc + (size_t)(h0 + r) * NPIX + kt * BK + cs * 8,
                  &As[buf][chunk * 8]);
        }
        #pragma unroll
        for (int it = 0; it < 2; ++it) {
            int chunk = it * 256 + tid;
            int r = chunk >> 2, c = chunk & 3;
            int cs = c ^ (r & 3) ^ ((r >> 2) & 3);
            GLD16(D + (size_t)(l0 + r) * NPIX + kt * BK + cs * 8,
                  &Bs[buf][chunk * 8]);
        }
    };

    stage(0, 0);
    int cur = 0;
    for (int kt = 0; kt < NKT; ++kt) {
        __syncthreads();
        if (kt + 1 < NKT) stage(kt + 1, cur ^ 1);

        bf16x8 af[4], bfr[4];
        #pragma unroll
        for (int m = 0; m < 4; ++m) {
            int row = wr * 64 + m * 16 + rm;
            int c = kq ^ (row & 3) ^ ((row >> 2) & 3);
            af[m] = *(const bf16x8*)&As[cur][row * BK + c * 8];
        }
        #pragma unroll
        for (int n = 0; n < 4; ++n) {
            int row = wc * 64 + n * 16 + rm;
            int c = kq ^ (row & 3) ^ ((row >> 2) & 3);
            bfr[n] = *(const bf16x8*)&Bs[cur][row * BK + c * 8];
        }
        #pragma unroll
        for (int m = 0; m < 4; ++m)
            #pragma unroll
            for (int n = 0; n < 4; ++n)
                acc[m][n] = __builtin_amdgcn_mfma_f32_16x16x32_bf16(
                    af[m], bfr[n], acc[m][n], 0, 0, 0);
        cur ^= 1;
    }

    // Transposed epilogue: sT[l][h], lane holds 4 contiguous h per fragment
    #pragma unroll
    for (int m = 0; m < 4; ++m) {
        int h = h0 + wr * 64 + m * 16 + kq * 4;
        #pragma unroll
        for (int n = 0; n < 4; ++n) {
            int l = l0 + wc * 64 + n * 16 + rm;
            ushort4 w;
            w.x = f2bf(acc[m][n][0]);
            w.y = f2bf(acc[m][n][1]);
            w.z = f2bf(acc[m][n][2]);
            w.w = f2bf(acc[m][n][3]);
            *(ushort4*)&sTbc[(size_t)l * NPIX + h] = w;
        }
    }
}

// ---------------- Stage 2: out[k][l] = (sum_h D[k][h]*sT[l][h]) * 1e-3 ----------------
__global__ __launch_bounds__(256) void k_stage2(
        const unsigned short* __restrict__ D,
        const unsigned short* __restrict__ sT,
        float* __restrict__ out) {
    __shared__ unsigned short As[2][BM * BK];          // bf16 D tile
    __shared__ unsigned short Bs[2][BN * BK];          // bf16 sT tile

    const int bc = blockIdx.z;
    const int k0 = blockIdx.y * BM;
    const int l0 = blockIdx.x * BN;
    const unsigned short* sTbc = sT + (size_t)bc * NPIX * NPIX;
    float* obc = out + (size_t)bc * NPIX * NPIX;

    const int tid  = threadIdx.x;
    const int lane = tid & 63;
    const int wid  = tid >> 6;
    const int wr = wid >> 1, wc = wid & 1;
    const int rm = lane & 15;
    const int kq = lane >> 4;

    f32x4 acc[4][4] = {};

    auto stage = [&](int kt, int buf) {
        #pragma unroll
        for (int it = 0; it < 2; ++it) {
            int chunk = it * 256 + tid;
            int r = chunk >> 2, c = chunk & 3;
            int cs = c ^ (r & 3) ^ ((r >> 2) & 3);
            GLD16(D + (size_t)(k0 + r) * NPIX + kt * BK + cs * 8,
                  &As[buf][chunk * 8]);
        }
        #pragma unroll
        for (int it = 0; it < 2; ++it) {
            int chunk = it * 256 + tid;
            int r = chunk >> 2, c = chunk & 3;
            int cs = c ^ (r & 3) ^ ((r >> 2) & 3);
            GLD16(sTbc + (size_t)(l0 + r) * NPIX + kt * BK + cs * 8,
                  &Bs[buf][chunk * 8]);
        }
    };

    stage(0, 0);
    int cur = 0;
    for (int kt = 0; kt < NKT; ++kt) {
        __syncthreads();
        if (kt + 1 < NKT) stage(kt + 1, cur ^ 1);

        bf16x8 af[4], bfr[4];
        #pragma unroll
        for (int m = 0; m < 4; ++m) {
            int row = wr * 64 + m * 16 + rm;
            int c = kq ^ (row & 3) ^ ((row >> 2) & 3);
            af[m] = *(const bf16x8*)&As[cur][row * BK + c * 8];
        }
        #pragma unroll
        for (int n = 0; n < 4; ++n) {
            int row = wc * 64 + n * 16 + rm;
            int c = kq ^ (row & 3) ^ ((row >> 2) & 3);
            bfr[n] = *(const bf16x8*)&Bs[cur][row * BK + c * 8];
        }
        #pragma unroll
        for (int m = 0; m < 4; ++m)
            #pragma unroll
            for (int n = 0; n < 4; ++n)
                acc[m][n] = __builtin_amdgcn_mfma_f32_16x16x32_bf16(
                    af[m], bfr[n], acc[m][n], 0, 0, 0);
        cur ^= 1;
    }

    #pragma unroll
    for (int m = 0; m < 4; ++m) {
        int k_ = k0 + wr * 64 + m * 16 + kq * 4;
        #pragma unroll
        for (int n = 0; n < 4; ++n) {
            int l_ = l0 + wc * 64 + n * 16 + rm;
            #pragma unroll
            for (int r = 0; r < 4; ++r)
                obc[(size_t)(k_ + r) * NPIX + l_] = acc[m][n][r] * 1.0e-3f;
        }
    }
}

extern "C" void kernel_launch(void* const* d_in, const int* in_sizes, int n_in,
                              void* d_out, int out_size, void* d_ws, size_t ws_size,
                              hipStream_t stream) {
    const float* img = (const float*)d_in[0];
    float* out = (float*)d_out;

    const size_t D_OFF   = 0;
    const size_t ST_OFF  = 512 * 1024;                        // 512 KB for D
    const size_t ST_SZ   = (size_t)NBC * NPIX * NPIX * 2;     // 48 MB
    const size_t XBF_SZ  = (size_t)NBC * NPIX * NPIX * 2;     // 48 MB

    unsigned short* D  = (unsigned short*)((char*)d_ws + D_OFF);
    unsigned short* sT = (unsigned short*)((char*)d_ws + ST_OFF);
    // Xbf: prefer ws; else use front of d_out (dead until stage2 overwrites it).
    unsigned short* Xbf;
    if (ws_size >= ST_OFF + ST_SZ + XBF_SZ)
        Xbf = (unsigned short*)((char*)d_ws + ST_OFF + ST_SZ);
    else
        Xbf = (unsigned short*)d_out;

    k_basis<<<dim3(512 * 512 / 256), dim3(256), 0, stream>>>(D);

    k_cvt<<<dim3((int)((size_t)NBC * NPIX * NPIX / 16 / 256)), dim3(256), 0, stream>>>(img, Xbf);

    k_stage1<<<dim3(NWG1), dim3(256), 0, stream>>>(Xbf, D, sT);

    dim3 grid2(NPIX / BN, NPIX / BM, NBC);
    k_stage2<<<grid2, dim3(256), 0, stream>>>(D, sT, out);
}

// Round 4
// 116.667 us; speedup vs baseline: 1.0244x; 1.0244x over previous
//
#include <hip/hip_runtime.h>
#include <hip/hip_bf16.h>
#include <stdint.h>

#define NPIX 512
#define NBC  96
#define BM 128
#define BN 128
#define BK 32
#define NKT 16
#define NWG (4 * 4 * NBC)   // 1536 blocks, 6 full rounds on 256 CUs

typedef __attribute__((ext_vector_type(8))) short bf16x8;
typedef __attribute__((ext_vector_type(4))) float f32x4;
typedef __attribute__((ext_vector_type(8))) unsigned short u16x8;

__device__ __forceinline__ unsigned short f2bf(float f) {
    __hip_bfloat16 h = __float2bfloat16(f);
    union { __hip_bfloat16 h; unsigned short u; } v;
    v.h = h;
    return v.u;
}

#define GLD16(g, l) __builtin_amdgcn_global_load_lds( \
    (const __attribute__((address_space(1))) void*)(const void*)(g), \
    (__attribute__((address_space(3))) void*)(void*)(l), 16, 0, 0)

// ---------------- D basis: D[k][n] = bf16(2*cos(pi*(2n+1)*k/1024)) ----------------
__global__ void k_basis(unsigned short* __restrict__ D) {
    int idx = blockIdx.x * 256 + threadIdx.x;
    int k = idx >> 9, n = idx & 511;
    int m = ((2 * n + 1) * k) & 2047;              // mod 4N keeps the cos arg small
    float ang = (float)m * 3.06796157577128218e-03f;  // pi/1024
    D[idx] = f2bf(2.0f * cosf(ang));
}

// ---------------- cvt: X fp32 -> bf16, 16 elems/thread ----------------
__global__ __launch_bounds__(256) void k_cvt(const float* __restrict__ X,
                                             unsigned short* __restrict__ Xbf) {
    size_t t = (size_t)blockIdx.x * 256 + threadIdx.x;
    const float4* src = (const float4*)X + t * 4;
    float4 a = src[0], b = src[1], c = src[2], d = src[3];
    u16x8 w0, w1;
    w0[0] = f2bf(a.x); w0[1] = f2bf(a.y); w0[2] = f2bf(a.z); w0[3] = f2bf(a.w);
    w0[4] = f2bf(b.x); w0[5] = f2bf(b.y); w0[6] = f2bf(b.z); w0[7] = f2bf(b.w);
    w1[0] = f2bf(c.x); w1[1] = f2bf(c.y); w1[2] = f2bf(c.z); w1[3] = f2bf(c.w);
    w1[4] = f2bf(d.x); w1[5] = f2bf(d.y); w1[6] = f2bf(d.z); w1[7] = f2bf(d.w);
    u16x8* dst = (u16x8*)Xbf + t * 2;
    dst[0] = w0;
    dst[1] = w1;
}

// ---------------- BT-GEMM: C = A(rows M, k-contig) x B(rows N, k-contig)^T ----------------
// 3-deep LDS staging pipeline, counted vmcnt (never 0 in steady state), raw barriers.
// TRANS_OUT=true : C = bf16 sT[N-idx][M-idx] via LDS-transposed coalesced epilogue (stage 1)
// TRANS_OUT=false: C = fp32 out[M-idx][N-idx] * 1e-3, direct stores (stage 2)
template<bool TRANS_OUT>
__global__ __launch_bounds__(256) void k_gemm(
        const unsigned short* __restrict__ A, size_t strideA,
        const unsigned short* __restrict__ B, size_t strideB,
        void* __restrict__ Cv) {
    __shared__ unsigned short LDS[24576];              // 48 KB: A0 A1 A2 B0 B1 B2 (8 KB each)

    // Bijective XCD-chunked swizzle: 1536 = 8 XCDs x 192 consecutive tiles.
    const int bid = blockIdx.x;
    const int nb  = (bid & 7) * (NWG / 8) + (bid >> 3);
    const int bxn = nb & 3, bym = (nb >> 2) & 3, bc = nb >> 4;
    const int m0 = bym * BM, n0 = bxn * BN;
    const unsigned short* Aimg = A + (size_t)bc * strideA;
    const unsigned short* Bimg = B + (size_t)bc * strideB;

    const int tid  = threadIdx.x;
    const int lane = tid & 63;
    const int wid  = tid >> 6;
    const int wr = wid >> 1, wc = wid & 1;             // 2x2 wave grid, 64x64 each
    const int rm = lane & 15;
    const int kq = lane >> 4;

    unsigned short *a0 = LDS,         *a1 = LDS + 4096,  *a2 = LDS + 8192;
    unsigned short *b0 = LDS + 12288, *b1 = LDS + 16384, *b2 = LDS + 20480;

    f32x4 acc[4][4] = {};

    auto stage = [&](int kt, unsigned short* Ab, unsigned short* Bb) {
        #pragma unroll
        for (int it = 0; it < 2; ++it) {
            int chunk = it * 256 + tid;
            int r = chunk >> 2, c = chunk & 3;
            int cs = c ^ (r & 3) ^ ((r >> 2) & 3);     // pre-swizzled source, linear dest
            GLD16(Aimg + (size_t)(m0 + r) * NPIX + kt * BK + cs * 8, Ab + chunk * 8);
        }
        #pragma unroll
        for (int it = 0; it < 2; ++it) {
            int chunk = it * 256 + tid;
            int r = chunk >> 2, c = chunk & 3;
            int cs = c ^ (r & 3) ^ ((r >> 2) & 3);
            GLD16(Bimg + (size_t)(n0 + r) * NPIX + kt * BK + cs * 8, Bb + chunk * 8);
        }
    };

    auto compute = [&](const unsigned short* Ab, const unsigned short* Bb) {
        bf16x8 af[4], bfr[4];
        #pragma unroll
        for (int m = 0; m < 4; ++m) {
            int row = wr * 64 + m * 16 + rm;
            int c = kq ^ (row & 3) ^ ((row >> 2) & 3);
            af[m] = *(const bf16x8*)&Ab[row * BK + c * 8];
        }
        #pragma unroll
        for (int n = 0; n < 4; ++n) {
            int row = wc * 64 + n * 16 + rm;
            int c = kq ^ (row & 3) ^ ((row >> 2) & 3);
            bfr[n] = *(const bf16x8*)&Bb[row * BK + c * 8];
        }
        __builtin_amdgcn_s_setprio(1);
        #pragma unroll
        for (int m = 0; m < 4; ++m)
            #pragma unroll
            for (int n = 0; n < 4; ++n)
                acc[m][n] = __builtin_amdgcn_mfma_f32_16x16x32_bf16(
                    af[m], bfr[n], acc[m][n], 0, 0, 0);
        __builtin_amdgcn_s_setprio(0);
    };

    stage(0, a0, b0);
    stage(1, a1, b1);                                  // 8 loads/thread in flight

    for (int t = 0; t < NKT - 1; ++t) {
        // Wait only for the oldest stage (ours); next stage stays in flight.
        asm volatile("s_waitcnt vmcnt(4)" ::: "memory");
        __builtin_amdgcn_sched_barrier(0);
        __builtin_amdgcn_s_barrier();                  // all waves: tile t complete
        __builtin_amdgcn_sched_barrier(0);
        if (t + 2 < NKT) stage(t + 2, a2, b2);         // keep 2 tiles in flight
        compute(a0, b0);
        unsigned short* ta = a0; a0 = a1; a1 = a2; a2 = ta;
        unsigned short* tb = b0; b0 = b1; b1 = b2; b2 = tb;
    }
    // Peeled last iteration: drain everything.
    asm volatile("s_waitcnt vmcnt(0)" ::: "memory");
    __builtin_amdgcn_sched_barrier(0);
    __builtin_amdgcn_s_barrier();
    __builtin_amdgcn_sched_barrier(0);
    compute(a0, b0);

    if constexpr (TRANS_OUT) {
        // Transposed epilogue via LDS: coalesced 16B writes of sT[l][h].
        __builtin_amdgcn_s_barrier();                  // staging LDS now dead for all waves
        __builtin_amdgcn_sched_barrier(0);
        char* Ts = (char*)LDS;                         // 32 KB tile overlay
        #pragma unroll
        for (int m = 0; m < 4; ++m) {
            int hb = wr * 64 + m * 16 + kq * 4;
            #pragma unroll
            for (int n = 0; n < 4; ++n) {
                int l = wc * 64 + n * 16 + rm;
                int byte = (l * 256 + hb * 2) ^ ((l & 7) << 4);
                ushort4 w;
                w.x = f2bf(acc[m][n][0]);
                w.y = f2bf(acc[m][n][1]);
                w.z = f2bf(acc[m][n][2]);
                w.w = f2bf(acc[m][n][3]);
                *(ushort4*)(Ts + byte) = w;
            }
        }
        __builtin_amdgcn_s_barrier();
        __builtin_amdgcn_sched_barrier(0);
        unsigned short* Co = (unsigned short*)Cv + (size_t)bc * NPIX * NPIX;
        int row = tid >> 1, half = tid & 1;
        #pragma unroll
        for (int c2 = 0; c2 < 8; ++c2) {
            int rb = (row * 256 + half * 128 + c2 * 16) ^ ((row & 7) << 4);
            u16x8 v = *(const u16x8*)(Ts + rb);
            *(u16x8*)&Co[(size_t)(n0 + row) * NPIX + m0 + half * 64 + c2 * 8] = v;
        }
    } else {
        float* Co = (float*)Cv + (size_t)bc * NPIX * NPIX;
        #pragma unroll
        for (int m = 0; m < 4; ++m) {
            int k_ = m0 + wr * 64 + m * 16 + kq * 4;
            #pragma unroll
            for (int n = 0; n < 4; ++n) {
                int l_ = n0 + wc * 64 + n * 16 + rm;
                #pragma unroll
                for (int r = 0; r < 4; ++r)
                    Co[(size_t)(k_ + r) * NPIX + l_] = acc[m][n][r] * 1.0e-3f;
            }
        }
    }
}

extern "C" void kernel_launch(void* const* d_in, const int* in_sizes, int n_in,
                              void* d_out, int out_size, void* d_ws, size_t ws_size,
                              hipStream_t stream) {
    const float* img = (const float*)d_in[0];
    float* out = (float*)d_out;

    const size_t ST_OFF = 512 * 1024;                     // 512 KB for D
    const size_t ST_SZ  = (size_t)NBC * NPIX * NPIX * 2;  // 48 MB
    const size_t XBF_SZ = ST_SZ;

    unsigned short* D  = (unsigned short*)d_ws;
    unsigned short* sT = (unsigned short*)((char*)d_ws + ST_OFF);
    unsigned short* Xbf;
    if (ws_size >= ST_OFF + ST_SZ + XBF_SZ)
        Xbf = (unsigned short*)((char*)d_ws + ST_OFF + ST_SZ);
    else
        Xbf = (unsigned short*)d_out;                     // dead until stage2 overwrites

    k_basis<<<dim3(512 * 512 / 256), dim3(256), 0, stream>>>(D);
    k_cvt<<<dim3((int)((size_t)NBC * NPIX * NPIX / 16 / 256)), dim3(256), 0, stream>>>(img, Xbf);

    // Stage 1: sT[l][h] = bf16( (Xbf @ D^T)[h][l] )
    k_gemm<true><<<dim3(NWG), dim3(256), 0, stream>>>(
        Xbf, (size_t)NPIX * NPIX, D, 0, (void*)sT);
    // Stage 2: out[k][l] = (D @ sT^T)[k][l] * 1e-3
    k_gemm<false><<<dim3(NWG), dim3(256), 0, stream>>>(
        D, 0, sT, (size_t)NPIX * NPIX, (void*)out);
}

// Round 5
// 111.161 us; speedup vs baseline: 1.0752x; 1.0495x over previous
//
#include <hip/hip_runtime.h>
#include <hip/hip_bf16.h>
#include <stdint.h>

#define NPIX 512
#define NBC  96
#define NWG8 (NBC * 4)      // 384 blocks: 96 images x 2x2 tiles of 256^2

typedef __attribute__((ext_vector_type(8))) short bf16x8;
typedef __attribute__((ext_vector_type(4))) float f32x4;
typedef __attribute__((ext_vector_type(8))) unsigned short u16x8;

__device__ __forceinline__ unsigned short f2bf(float f) {
    __hip_bfloat16 h = __float2bfloat16(f);
    union { __hip_bfloat16 h; unsigned short u; } v;
    v.h = h;
    return v.u;
}

#define GLD16(g, l) __builtin_amdgcn_global_load_lds( \
    (const __attribute__((address_space(1))) void*)(const void*)(g), \
    (__attribute__((address_space(3))) void*)(void*)(l), 16, 0, 0)

#define SBAR() do { __builtin_amdgcn_sched_barrier(0); \
                    __builtin_amdgcn_s_barrier(); \
                    __builtin_amdgcn_sched_barrier(0); } while (0)
#define LGKM0() do { asm volatile("s_waitcnt lgkmcnt(0)" ::: "memory"); \
                     __builtin_amdgcn_sched_barrier(0); } while (0)

// ---------------- D basis: D[k][n] = bf16(2*cos(pi*(2n+1)*k/1024)) ----------------
__global__ void k_basis(unsigned short* __restrict__ D) {
    int idx = blockIdx.x * 256 + threadIdx.x;
    int k = idx >> 9, n = idx & 511;
    int m = ((2 * n + 1) * k) & 2047;
    float ang = (float)m * 3.06796157577128218e-03f;  // pi/1024
    D[idx] = f2bf(2.0f * cosf(ang));
}

// ---------------- cvt: X fp32 -> bf16, 16 elems/thread ----------------
__global__ __launch_bounds__(256) void k_cvt(const float* __restrict__ X,
                                             unsigned short* __restrict__ Xbf) {
    size_t t = (size_t)blockIdx.x * 256 + threadIdx.x;
    const float4* src = (const float4*)X + t * 4;
    float4 a = src[0], b = src[1], c = src[2], d = src[3];
    u16x8 w0, w1;
    w0[0] = f2bf(a.x); w0[1] = f2bf(a.y); w0[2] = f2bf(a.z); w0[3] = f2bf(a.w);
    w0[4] = f2bf(b.x); w0[5] = f2bf(b.y); w0[6] = f2bf(b.z); w0[7] = f2bf(b.w);
    w1[0] = f2bf(c.x); w1[1] = f2bf(c.y); w1[2] = f2bf(c.z); w1[3] = f2bf(c.w);
    w1[4] = f2bf(d.x); w1[5] = f2bf(d.y); w1[6] = f2bf(d.z); w1[7] = f2bf(d.w);
    u16x8* dst = (u16x8*)Xbf + t * 2;
    dst[0] = w0;
    dst[1] = w1;
}

// ------------- 256^2 8-phase BT-GEMM: C = A(M rows,k-contig) x B(N rows,k-contig)^T -------------
// 8 waves (2M x 4N), BK=64, 8 K-tiles; 4 phases/K-tile (C-quadrants mh x nh), 16 MFMA each;
// one half-tile staged per phase via global_load_lds; counted vmcnt(4), never 0 until tail.
// TRANS_OUT=true : C -> bf16 sT[N-idx][M-idx] via 128KB LDS-overlay transposed epilogue.
// TRANS_OUT=false: C -> fp32 out[M-idx][N-idx] * 1e-3.
template<bool TRANS_OUT>
__global__ __launch_bounds__(512) void k_gemm8(
        const unsigned short* __restrict__ A, size_t strideA,
        const unsigned short* __restrict__ B, size_t strideB,
        void* __restrict__ Cv) {
    __shared__ __align__(16) char LDS[131072];   // [A p0|A p1|B p0|B p1], 32KB each, halves of 16KB

    // Bijective XCD-chunked swizzle: 384 = 8 XCDs x 48 consecutive tiles.
    const int bid = blockIdx.x;
    const int nb  = (bid & 7) * (NWG8 / 8) + (bid >> 3);
    const int bc = nb >> 2, mt = (nb >> 1) & 1, nt = nb & 1;
    const int mA0 = mt * 256, nB0 = nt * 256;
    const unsigned short* Aimg = A + (size_t)bc * strideA;
    const unsigned short* Bimg = B + (size_t)bc * strideB;

    const int tid  = threadIdx.x;
    const int lane = tid & 63;
    const int wid  = tid >> 6;
    const int wr = wid >> 2, wc = wid & 3;     // 2 x 4 wave grid; wave C = 128 x 64
    const int rm = lane & 15;
    const int kq = lane >> 4;

    f32x4 acc[8][4] = {};
    bf16x8 a[4][2], b0[2][2], b1[2][2];

    // --- staging: one half-tile (128 rows x 64 cols bf16 = 16KB) into slot p, half H ---
    auto stageA = [&](int kt, int p, int H) {
        char* dst = LDS + p * 32768 + H * 16384;
        #pragma unroll
        for (int it = 0; it < 2; ++it) {
            int c = it * 512 + tid;
            int rp = c >> 3, g = c & 7;
            int gs = g ^ (rp & 7);                         // inverse swizzle on SOURCE
            int row = ((rp >> 6) << 7) + H * 64 + (rp & 63);
            GLD16(Aimg + (size_t)(mA0 + row) * NPIX + kt * 64 + gs * 8, dst + c * 16);
        }
    };
    auto stageB = [&](int kt, int p, int H) {
        char* dst = LDS + 65536 + p * 32768 + H * 16384;
        #pragma unroll
        for (int it = 0; it < 2; ++it) {
            int c = it * 512 + tid;
            int rp = c >> 3, g = c & 7;
            int gs = g ^ (rp & 7);
            int row = ((rp >> 5) << 6) + H * 32 + (rp & 31);
            GLD16(Bimg + (size_t)(nB0 + row) * NPIX + kt * 64 + gs * 8, dst + c * 16);
        }
    };

    // --- fragment reads (swizzled ds_read_b128) ---
    auto readA = [&](int p, int mh) {
        const char* base = LDS + p * 32768 + mh * 16384;
        #pragma unroll
        for (int f = 0; f < 4; ++f) {
            int rp = wr * 64 + f * 16 + rm;
            #pragma unroll
            for (int ks = 0; ks < 2; ++ks) {
                int slot = (ks * 4 + kq) ^ (rm & 7);
                a[f][ks] = *(const bf16x8*)(base + rp * 128 + slot * 16);
            }
        }
    };
    auto readB = [&](int p, int nh, bf16x8 (&b)[2][2]) {
        const char* base = LDS + 65536 + p * 32768 + nh * 16384;
        #pragma unroll
        for (int jj = 0; jj < 2; ++jj) {
            int rp = wc * 32 + jj * 16 + rm;
            #pragma unroll
            for (int ks = 0; ks < 2; ++ks) {
                int slot = (ks * 4 + kq) ^ (rm & 7);
                b[jj][ks] = *(const bf16x8*)(base + rp * 128 + slot * 16);
            }
        }
    };
    auto mma = [&](int mh, int nh, bf16x8 (&b)[2][2]) {
        __builtin_amdgcn_s_setprio(1);
        #pragma unroll
        for (int f = 0; f < 4; ++f)
            #pragma unroll
            for (int jj = 0; jj < 2; ++jj)
                #pragma unroll
                for (int ks = 0; ks < 2; ++ks)
                    acc[mh * 4 + f][nh * 2 + jj] = __builtin_amdgcn_mfma_f32_16x16x32_bf16(
                        a[f][ks], b[jj][ks], acc[mh * 4 + f][nh * 2 + jj], 0, 0, 0);
        __builtin_amdgcn_s_setprio(0);
    };

    // --- prologue: K-tile 0 into slot 0, issue order Ah0 Bh0 Bh1 Ah1 ---
    stageA(0, 0, 0); stageB(0, 0, 0); stageB(0, 0, 1); stageA(0, 0, 1);

    for (int T = 0; T < 7; ++T) {
        const int p = T & 1, pn = p ^ 1;
        // q0: (mh0,nh0) — needs Ah0,Bh0; newest-4 loads may be Bh1,Ah1
        asm volatile("s_waitcnt vmcnt(4)" ::: "memory"); SBAR();
        readA(p, 0); readB(p, 0, b0); stageA(T + 1, pn, 0);
        LGKM0(); mma(0, 0, b0);
        // q1: (mh0,nh1) — needs Bh1; newer: Ah1 + A'{h0} = 4
        asm volatile("s_waitcnt vmcnt(4)" ::: "memory"); SBAR();
        readB(p, 1, b1); stageB(T + 1, pn, 0);
        LGKM0(); mma(0, 1, b1);
        // q2: (mh1,nh0) — needs Ah1; newer: A'h0 + B'h0 = 4
        asm volatile("s_waitcnt vmcnt(4)" ::: "memory"); SBAR();
        readA(p, 1); stageB(T + 1, pn, 1);
        LGKM0(); mma(1, 0, b0);
        // q3: (mh1,nh1) — nothing new needed
        SBAR();
        stageA(T + 1, pn, 1);
        mma(1, 1, b1);
    }
    {   // peeled last K-tile (T=7, slot 1): drain with counted tail 4 -> 2 -> 0
        asm volatile("s_waitcnt vmcnt(4)" ::: "memory"); SBAR();
        readA(1, 0); readB(1, 0, b0); LGKM0(); mma(0, 0, b0);
        asm volatile("s_waitcnt vmcnt(2)" ::: "memory"); SBAR();
        readB(1, 1, b1); LGKM0(); mma(0, 1, b1);
        asm volatile("s_waitcnt vmcnt(0)" ::: "memory"); SBAR();
        readA(1, 1); LGKM0(); mma(1, 0, b0);
        SBAR();
        mma(1, 1, b1);
    }

    if constexpr (TRANS_OUT) {
        // Transposed bf16 epilogue through the (now dead) 128KB staging LDS.
        SBAR();
        #pragma unroll
        for (int mh = 0; mh < 2; ++mh)
            #pragma unroll
            for (int f = 0; f < 4; ++f) {
                int h_loc = wr * 128 + mh * 64 + f * 16 + kq * 4;
                #pragma unroll
                for (int nh = 0; nh < 2; ++nh)
                    #pragma unroll
                    for (int jj = 0; jj < 2; ++jj) {
                        int l_loc = wc * 64 + (nh * 2 + jj) * 16 + rm;
                        int byte = (l_loc * 512 + h_loc * 2) ^ ((l_loc & 7) << 4);
                        f32x4 v = acc[mh * 4 + f][nh * 2 + jj];
                        ushort4 w;
                        w.x = f2bf(v[0]); w.y = f2bf(v[1]);
                        w.z = f2bf(v[2]); w.w = f2bf(v[3]);
                        *(ushort4*)(LDS + byte) = w;
                    }
            }
        LGKM0(); SBAR();
        unsigned short* Co = (unsigned short*)Cv + (size_t)bc * NPIX * NPIX;
        #pragma unroll
        for (int i = 0; i < 16; ++i) {
            int chunk = i * 512 + tid;
            int l_loc = chunk >> 5, g = chunk & 31;
            int byte = (l_loc * 512 + g * 16) ^ ((l_loc & 7) << 4);
            u16x8 v = *(const u16x8*)(LDS + byte);
            *(u16x8*)&Co[(size_t)(nB0 + l_loc) * NPIX + mA0 + g * 8] = v;
        }
    } else {
        float* Co = (float*)Cv + (size_t)bc * NPIX * NPIX;
        #pragma unroll
        for (int mh = 0; mh < 2; ++mh)
            #pragma unroll
            for (int f = 0; f < 4; ++f) {
                int k_ = mA0 + wr * 128 + mh * 64 + f * 16 + kq * 4;
                #pragma unroll
                for (int nh = 0; nh < 2; ++nh)
                    #pragma unroll
                    for (int jj = 0; jj < 2; ++jj) {
                        int l_ = nB0 + wc * 64 + (nh * 2 + jj) * 16 + rm;
                        f32x4 v = acc[mh * 4 + f][nh * 2 + jj];
                        #pragma unroll
                        for (int r = 0; r < 4; ++r)
                            Co[(size_t)(k_ + r) * NPIX + l_] = v[r] * 1.0e-3f;
                    }
            }
    }
}

extern "C" void kernel_launch(void* const* d_in, const int* in_sizes, int n_in,
                              void* d_out, int out_size, void* d_ws, size_t ws_size,
                              hipStream_t stream) {
    const float* img = (const float*)d_in[0];
    float* out = (float*)d_out;

    const size_t ST_OFF = 512 * 1024;                     // 512 KB for D
    const size_t ST_SZ  = (size_t)NBC * NPIX * NPIX * 2;  // 48 MB
    const size_t XBF_SZ = ST_SZ;

    unsigned short* D  = (unsigned short*)d_ws;
    unsigned short* sT = (unsigned short*)((char*)d_ws + ST_OFF);
    unsigned short* Xbf;
    if (ws_size >= ST_OFF + ST_SZ + XBF_SZ)
        Xbf = (unsigned short*)((char*)d_ws + ST_OFF + ST_SZ);
    else
        Xbf = (unsigned short*)d_out;                     // dead until stage2 overwrites

    k_basis<<<dim3(512 * 512 / 256), dim3(256), 0, stream>>>(D);
    k_cvt<<<dim3((int)((size_t)NBC * NPIX * NPIX / 16 / 256)), dim3(256), 0, stream>>>(img, Xbf);

    // Stage 1: sT[l][h] = bf16( (Xbf @ D^T)[h][l] )
    k_gemm8<true><<<dim3(NWG8), dim3(512), 0, stream>>>(
        Xbf, (size_t)NPIX * NPIX, D, 0, (void*)sT);
    // Stage 2: out[k][l] = (D @ sT^T)[k][l] * 1e-3
    k_gemm8<false><<<dim3(NWG8), dim3(512), 0, stream>>>(
        D, 0, sT, (size_t)NPIX * NPIX, (void*)out);
}

// Round 6
// 99.143 us; speedup vs baseline: 1.2055x; 1.1212x over previous
//
#include <hip/hip_runtime.h>
#include <hip/hip_bf16.h>
#include <stdint.h>

#define NPIX 512
#define NBC  96
#define NWG8 (NBC * 4)      // 384 blocks: 96 images x 2x2 tiles of 256^2

typedef __attribute__((ext_vector_type(8))) short bf16x8;
typedef __attribute__((ext_vector_type(4))) float f32x4;
typedef __attribute__((ext_vector_type(8))) unsigned short u16x8;

__device__ __forceinline__ unsigned short f2bf(float f) {
    __hip_bfloat16 h = __float2bfloat16(f);
    union { __hip_bfloat16 h; unsigned short u; } v;
    v.h = h;
    return v.u;
}

#define GLD16(g, l) __builtin_amdgcn_global_load_lds( \
    (const __attribute__((address_space(1))) void*)(const void*)(g), \
    (__attribute__((address_space(3))) void*)(void*)(l), 16, 0, 0)

#define SBAR() do { __builtin_amdgcn_sched_barrier(0); \
                    __builtin_amdgcn_s_barrier(); \
                    __builtin_amdgcn_sched_barrier(0); } while (0)
#define LGKM0() do { asm volatile("s_waitcnt lgkmcnt(0)" ::: "memory"); \
                     __builtin_amdgcn_sched_barrier(0); } while (0)
#define SB0() __builtin_amdgcn_sched_barrier(0)

// ---------------- D basis: D[k][n] = bf16(2*cos(pi*(2n+1)*k/1024)) ----------------
__global__ void k_basis(unsigned short* __restrict__ D) {
    int idx = blockIdx.x * 256 + threadIdx.x;
    int k = idx >> 9, n = idx & 511;
    int m = ((2 * n + 1) * k) & 2047;
    float ang = (float)m * 3.06796157577128218e-03f;  // pi/1024
    D[idx] = f2bf(2.0f * cosf(ang));
}

// ------------- Stage 1 (fused cvt): sT[l][h] = bf16( (X @ D^T)[h][l] ), X fp32 -------------
// 8-phase 256^2 schedule; A (X, fp32) reg-staged issue-early/cvt+ds_write-late;
// B (D, bf16) via global_load_lds. Wait ledger (per-thread FIFO):
//   q0: lgkm only | q1: vmcnt(6) | q2: vmcnt(8) -> write A'h0 | q3: vmcnt(2) -> write A'h1
__global__ __launch_bounds__(512) void k_s1fused(
        const float* __restrict__ X,
        const unsigned short* __restrict__ D,
        unsigned short* __restrict__ sT) {
    __shared__ __align__(16) char LDS[131072];   // A: 2 slots x 32KB | B: 2 slots x 32KB

    const int bid = blockIdx.x;
    const int nb  = (bid & 7) * (NWG8 / 8) + (bid >> 3);
    const int bc = nb >> 2, mt = (nb >> 1) & 1, nt = nb & 1;
    const int mA0 = mt * 256, nB0 = nt * 256;
    const float* Ximg = X + (size_t)bc * NPIX * NPIX;

    const int tid  = threadIdx.x;
    const int lane = tid & 63;
    const int wid  = tid >> 6;
    const int wr = wid >> 2, wc = wid & 3;     // 2 x 4 wave grid; wave C = 128 x 64
    const int rm = lane & 15;
    const int kq = lane >> 4;

    // A staging coords: thread covers row-slot rpA, 16-fp32 quarter qA of a 128x64 half-tile
    const int rpA = tid >> 2, qA = tid & 3;
    const int rowLocalBase = ((rpA >> 6) << 7) + (rpA & 63);   // + H*64 at use

    f32x4 acc[8][4] = {};
    bf16x8 a[4][2], b0[2][2], b1[2][2];
    float4 av0[4], av1[4];

    auto issueA = [&](int kt, int H, float4 (&av)[4]) {
        const float* src = Ximg + (size_t)(mA0 + rowLocalBase + H * 64) * NPIX
                                + kt * 64 + qA * 16;
        av[0] = *(const float4*)(src + 0);
        av[1] = *(const float4*)(src + 4);
        av[2] = *(const float4*)(src + 8);
        av[3] = *(const float4*)(src + 12);
    };
    auto writeAh = [&](int p, int H, float4 (&av)[4]) {
        char* dst = LDS + p * 32768 + H * 16384 + rpA * 128;
        u16x8 w0, w1;
        w0[0] = f2bf(av[0].x); w0[1] = f2bf(av[0].y); w0[2] = f2bf(av[0].z); w0[3] = f2bf(av[0].w);
        w0[4] = f2bf(av[1].x); w0[5] = f2bf(av[1].y); w0[6] = f2bf(av[1].z); w0[7] = f2bf(av[1].w);
        w1[0] = f2bf(av[2].x); w1[1] = f2bf(av[2].y); w1[2] = f2bf(av[2].z); w1[3] = f2bf(av[2].w);
        w1[4] = f2bf(av[3].x); w1[5] = f2bf(av[3].y); w1[6] = f2bf(av[3].z); w1[7] = f2bf(av[3].w);
        *(u16x8*)(dst + (((qA * 2 + 0) ^ (rpA & 7)) * 16)) = w0;
        *(u16x8*)(dst + (((qA * 2 + 1) ^ (rpA & 7)) * 16)) = w1;
    };
    auto stageBg = [&](int kt, int p, int H) {
        char* dst = LDS + 65536 + p * 32768 + H * 16384;
        #pragma unroll
        for (int it = 0; it < 2; ++it) {
            int c = it * 512 + tid;
            int rp = c >> 3, g = c & 7;
            int gs = g ^ (rp & 7);
            int row = ((rp >> 5) << 6) + H * 32 + (rp & 31);
            GLD16(D + (size_t)(nB0 + row) * NPIX + kt * 64 + gs * 8, dst + c * 16);
        }
    };
    auto readA = [&](int p, int mh) {
        const char* base = LDS + p * 32768 + mh * 16384;
        #pragma unroll
        for (int f = 0; f < 4; ++f) {
            int rp = wr * 64 + f * 16 + rm;
            #pragma unroll
            for (int ks = 0; ks < 2; ++ks) {
                int slot = (ks * 4 + kq) ^ (rm & 7);
                a[f][ks] = *(const bf16x8*)(base + rp * 128 + slot * 16);
            }
        }
    };
    auto readB = [&](int p, int nh, bf16x8 (&b)[2][2]) {
        const char* base = LDS + 65536 + p * 32768 + nh * 16384;
        #pragma unroll
        for (int jj = 0; jj < 2; ++jj) {
            int rp = wc * 32 + jj * 16 + rm;
            #pragma unroll
            for (int ks = 0; ks < 2; ++ks) {
                int slot = (ks * 4 + kq) ^ (rm & 7);
                b[jj][ks] = *(const bf16x8*)(base + rp * 128 + slot * 16);
            }
        }
    };
    auto mma = [&](int mh, int nh, bf16x8 (&b)[2][2]) {
        __builtin_amdgcn_s_setprio(1);
        #pragma unroll
        for (int f = 0; f < 4; ++f)
            #pragma unroll
            for (int jj = 0; jj < 2; ++jj)
                #pragma unroll
                for (int ks = 0; ks < 2; ++ks)
                    acc[mh * 4 + f][nh * 2 + jj] = __builtin_amdgcn_mfma_f32_16x16x32_bf16(
                        a[f][ks], b[jj][ks], acc[mh * 4 + f][nh * 2 + jj], 0, 0, 0);
        __builtin_amdgcn_s_setprio(0);
    };

    // --- prologue: tile 0 into slot 0 ---
    issueA(0, 0, av0); SB0();
    stageBg(0, 0, 0);  SB0();
    issueA(0, 1, av1); SB0();
    stageBg(0, 0, 1);  SB0();
    asm volatile("s_waitcnt vmcnt(8)" ::: "memory"); SB0();
    writeAh(0, 0, av0);
    asm volatile("s_waitcnt vmcnt(2)" ::: "memory"); SB0();
    writeAh(0, 1, av1);

    for (int T = 0; T < 7; ++T) {
        const int p = T & 1, pn = p ^ 1;
        // q0: reads A-h0,B-h0; issues next A-h0 regs + B-h0 GLD
        asm volatile("s_waitcnt lgkmcnt(0)" ::: "memory");
        SBAR();
        readA(p, 0); readB(p, 0, b0);
        issueA(T + 1, 0, av0); SB0();
        stageBg(T + 1, pn, 0); SB0();
        LGKM0(); mma(0, 0, b0);
        // q1: reads B-h1; issues next A-h1 regs + B-h1 GLD
        asm volatile("s_waitcnt vmcnt(6)" ::: "memory");
        SBAR();
        readB(p, 1, b1);
        issueA(T + 1, 1, av1); SB0();
        stageBg(T + 1, pn, 1); SB0();
        LGKM0(); mma(0, 1, b1);
        // q2: reads A-h1; cvt+write next A-h0
        asm volatile("s_waitcnt vmcnt(8)" ::: "memory");
        SBAR();
        readA(p, 1);
        LGKM0();
        writeAh(pn, 0, av0); SB0();
        mma(1, 0, b0);
        // q3: cvt+write next A-h1
        asm volatile("s_waitcnt vmcnt(2)" ::: "memory");
        asm volatile("s_waitcnt lgkmcnt(0)" ::: "memory");
        SBAR();
        writeAh(pn, 1, av1); SB0();
        mma(1, 1, b1);
    }
    {   // peeled last K-tile (T=7, slot 1)
        asm volatile("s_waitcnt lgkmcnt(0)" ::: "memory");
        SBAR();
        readA(1, 0); readB(1, 0, b0); LGKM0(); mma(0, 0, b0);
        asm volatile("s_waitcnt vmcnt(0)" ::: "memory");
        SBAR();
        readB(1, 1, b1); LGKM0(); mma(0, 1, b1);
        SBAR();
        readA(1, 1); LGKM0(); mma(1, 0, b0);
        SBAR();
        mma(1, 1, b1);
    }

    // Transposed bf16 epilogue through the (now dead) 128KB staging LDS.
    SBAR();
    #pragma unroll
    for (int mh = 0; mh < 2; ++mh)
        #pragma unroll
        for (int f = 0; f < 4; ++f) {
            int h_loc = wr * 128 + mh * 64 + f * 16 + kq * 4;
            #pragma unroll
            for (int nh = 0; nh < 2; ++nh)
                #pragma unroll
                for (int jj = 0; jj < 2; ++jj) {
                    int l_loc = wc * 64 + (nh * 2 + jj) * 16 + rm;
                    int byte = (l_loc * 512 + h_loc * 2) ^ ((l_loc & 7) << 4);
                    f32x4 v = acc[mh * 4 + f][nh * 2 + jj];
                    ushort4 w;
                    w.x = f2bf(v[0]); w.y = f2bf(v[1]);
                    w.z = f2bf(v[2]); w.w = f2bf(v[3]);
                    *(ushort4*)(LDS + byte) = w;
                }
        }
    LGKM0(); SBAR();
    unsigned short* Co = sT + (size_t)bc * NPIX * NPIX;
    #pragma unroll
    for (int i = 0; i < 16; ++i) {
        int chunk = i * 512 + tid;
        int l_loc = chunk >> 5, g = chunk & 31;
        int byte = (l_loc * 512 + g * 16) ^ ((l_loc & 7) << 4);
        u16x8 v = *(const u16x8*)(LDS + byte);
        *(u16x8*)&Co[(size_t)(nB0 + l_loc) * NPIX + mA0 + g * 8] = v;
    }
}

// ------------- Stage 2: out[k][l] = (D @ sT^T)[k][l] * 1e-3 (unchanged from R5) -------------
__global__ __launch_bounds__(512) void k_gemm8(
        const unsigned short* __restrict__ A, size_t strideA,
        const unsigned short* __restrict__ B, size_t strideB,
        float* __restrict__ Cv) {
    __shared__ __align__(16) char LDS[131072];

    const int bid = blockIdx.x;
    const int nb  = (bid & 7) * (NWG8 / 8) + (bid >> 3);
    const int bc = nb >> 2, mt = (nb >> 1) & 1, nt = nb & 1;
    const int mA0 = mt * 256, nB0 = nt * 256;
    const unsigned short* Aimg = A + (size_t)bc * strideA;
    const unsigned short* Bimg = B + (size_t)bc * strideB;

    const int tid  = threadIdx.x;
    const int lane = tid & 63;
    const int wid  = tid >> 6;
    const int wr = wid >> 2, wc = wid & 3;
    const int rm = lane & 15;
    const int kq = lane >> 4;

    f32x4 acc[8][4] = {};
    bf16x8 a[4][2], b0[2][2], b1[2][2];

    auto stageA = [&](int kt, int p, int H) {
        char* dst = LDS + p * 32768 + H * 16384;
        #pragma unroll
        for (int it = 0; it < 2; ++it) {
            int c = it * 512 + tid;
            int rp = c >> 3, g = c & 7;
            int gs = g ^ (rp & 7);
            int row = ((rp >> 6) << 7) + H * 64 + (rp & 63);
            GLD16(Aimg + (size_t)(mA0 + row) * NPIX + kt * 64 + gs * 8, dst + c * 16);
        }
    };
    auto stageB = [&](int kt, int p, int H) {
        char* dst = LDS + 65536 + p * 32768 + H * 16384;
        #pragma unroll
        for (int it = 0; it < 2; ++it) {
            int c = it * 512 + tid;
            int rp = c >> 3, g = c & 7;
            int gs = g ^ (rp & 7);
            int row = ((rp >> 5) << 6) + H * 32 + (rp & 31);
            GLD16(Bimg + (size_t)(nB0 + row) * NPIX + kt * 64 + gs * 8, dst + c * 16);
        }
    };
    auto readA = [&](int p, int mh) {
        const char* base = LDS + p * 32768 + mh * 16384;
        #pragma unroll
        for (int f = 0; f < 4; ++f) {
            int rp = wr * 64 + f * 16 + rm;
            #pragma unroll
            for (int ks = 0; ks < 2; ++ks) {
                int slot = (ks * 4 + kq) ^ (rm & 7);
                a[f][ks] = *(const bf16x8*)(base + rp * 128 + slot * 16);
            }
        }
    };
    auto readB = [&](int p, int nh, bf16x8 (&b)[2][2]) {
        const char* base = LDS + 65536 + p * 32768 + nh * 16384;
        #pragma unroll
        for (int jj = 0; jj < 2; ++jj) {
            int rp = wc * 32 + jj * 16 + rm;
            #pragma unroll
            for (int ks = 0; ks < 2; ++ks) {
                int slot = (ks * 4 + kq) ^ (rm & 7);
                b[jj][ks] = *(const bf16x8*)(base + rp * 128 + slot * 16);
            }
        }
    };
    auto mma = [&](int mh, int nh, bf16x8 (&b)[2][2]) {
        __builtin_amdgcn_s_setprio(1);
        #pragma unroll
        for (int f = 0; f < 4; ++f)
            #pragma unroll
            for (int jj = 0; jj < 2; ++jj)
                #pragma unroll
                for (int ks = 0; ks < 2; ++ks)
                    acc[mh * 4 + f][nh * 2 + jj] = __builtin_amdgcn_mfma_f32_16x16x32_bf16(
                        a[f][ks], b[jj][ks], acc[mh * 4 + f][nh * 2 + jj], 0, 0, 0);
        __builtin_amdgcn_s_setprio(0);
    };

    stageA(0, 0, 0); stageB(0, 0, 0); stageB(0, 0, 1); stageA(0, 0, 1);

    for (int T = 0; T < 7; ++T) {
        const int p = T & 1, pn = p ^ 1;
        asm volatile("s_waitcnt vmcnt(4)" ::: "memory"); SBAR();
        readA(p, 0); readB(p, 0, b0); stageA(T + 1, pn, 0);
        LGKM0(); mma(0, 0, b0);
        asm volatile("s_waitcnt vmcnt(4)" ::: "memory"); SBAR();
        readB(p, 1, b1); stageB(T + 1, pn, 0);
        LGKM0(); mma(0, 1, b1);
        asm volatile("s_waitcnt vmcnt(4)" ::: "memory"); SBAR();
        readA(p, 1); stageB(T + 1, pn, 1);
        LGKM0(); mma(1, 0, b0);
        SBAR();
        stageA(T + 1, pn, 1);
        mma(1, 1, b1);
    }
    {
        asm volatile("s_waitcnt vmcnt(4)" ::: "memory"); SBAR();
        readA(1, 0); readB(1, 0, b0); LGKM0(); mma(0, 0, b0);
        asm volatile("s_waitcnt vmcnt(2)" ::: "memory"); SBAR();
        readB(1, 1, b1); LGKM0(); mma(0, 1, b1);
        asm volatile("s_waitcnt vmcnt(0)" ::: "memory"); SBAR();
        readA(1, 1); LGKM0(); mma(1, 0, b0);
        SBAR();
        mma(1, 1, b1);
    }

    float* Co = Cv + (size_t)bc * NPIX * NPIX;
    #pragma unroll
    for (int mh = 0; mh < 2; ++mh)
        #pragma unroll
        for (int f = 0; f < 4; ++f) {
            int k_ = mA0 + wr * 128 + mh * 64 + f * 16 + kq * 4;
            #pragma unroll
            for (int nh = 0; nh < 2; ++nh)
                #pragma unroll
                for (int jj = 0; jj < 2; ++jj) {
                    int l_ = nB0 + wc * 64 + (nh * 2 + jj) * 16 + rm;
                    f32x4 v = acc[mh * 4 + f][nh * 2 + jj];
                    #pragma unroll
                    for (int r = 0; r < 4; ++r)
                        Co[(size_t)(k_ + r) * NPIX + l_] = v[r] * 1.0e-3f;
                }
        }
}

extern "C" void kernel_launch(void* const* d_in, const int* in_sizes, int n_in,
                              void* d_out, int out_size, void* d_ws, size_t ws_size,
                              hipStream_t stream) {
    const float* img = (const float*)d_in[0];
    float* out = (float*)d_out;

    unsigned short* D  = (unsigned short*)d_ws;                       // 512 KB
    unsigned short* sT = (unsigned short*)((char*)d_ws + 512 * 1024); // 48 MB

    k_basis<<<dim3(512 * 512 / 256), dim3(256), 0, stream>>>(D);

    // Stage 1 (fused fp32->bf16): sT[l][h] = bf16( (X @ D^T)[h][l] )
    k_s1fused<<<dim3(NWG8), dim3(512), 0, stream>>>(img, D, sT);

    // Stage 2: out[k][l] = (D @ sT^T)[k][l] * 1e-3
    k_gemm8<<<dim3(NWG8), dim3(512), 0, stream>>>(
        D, 0, sT, (size_t)NPIX * NPIX, out);
}